// Round 1
// baseline (2809.883 us; speedup 1.0000x reference)
//
#include <hip/hip_runtime.h>
#include <math.h>

#define NNODES 50000
#define NEDGES 800000
#define D 128

// ---------------- CSR build ----------------

__global__ __launch_bounds__(256) void count_kernel(const int* __restrict__ ei,
                                                    int* __restrict__ cnt) {
  int e = blockIdx.x * 256 + threadIdx.x;
  if (e < NEDGES) atomicAdd(&cnt[ei[NEDGES + e]], 1);
}

__global__ __launch_bounds__(1024) void scan_kernel(
    const int* __restrict__ cnt0, int* __restrict__ off0, int* __restrict__ cur0,
    const int* __restrict__ cnt1, int* __restrict__ off1, int* __restrict__ cur1) {
  const int* cnt = (blockIdx.x == 0) ? cnt0 : cnt1;
  int* off = (blockIdx.x == 0) ? off0 : off1;
  int* cur = (blockIdx.x == 0) ? cur0 : cur1;
  __shared__ int sm[1024];
  int tid = threadIdx.x;
  int running = 0;
  for (int base = 0; base < NNODES; base += 1024) {
    int idx = base + tid;
    int v = (idx < NNODES) ? cnt[idx] : 0;
    sm[tid] = v;
    __syncthreads();
    for (int o = 1; o < 1024; o <<= 1) {
      int t = (tid >= o) ? sm[tid - o] : 0;
      __syncthreads();
      sm[tid] += t;
      __syncthreads();
    }
    int excl = running + sm[tid] - v;  // exclusive prefix
    if (idx < NNODES) { off[idx] = excl; cur[idx] = excl; }
    running += sm[1023];
    __syncthreads();
  }
  if (tid == 0) off[NNODES] = running;
}

__global__ __launch_bounds__(256) void scatter_kernel(const int* __restrict__ ei,
                                                      int* __restrict__ cur,
                                                      int* __restrict__ list) {
  int e = blockIdx.x * 256 + threadIdx.x;
  if (e < NEDGES) {
    int s = ei[e];
    int d = ei[NEDGES + e];
    int pos = atomicAdd(&cur[d], 1);
    list[pos] = s;
  }
}

// ---------------- fused per-node kernel ----------------
// block = 128 threads (2 waves), one node per block; thread = one feature dim / output col.

__global__ __launch_bounds__(128) void fused_node_kernel(
    const float* __restrict__ x,
    const int* __restrict__ off0, const int* __restrict__ list0,
    const int* __restrict__ off1, const int* __restrict__ list1,
    const float* __restrict__ w_in, const float* __restrict__ b_in,
    const float* __restrict__ w_out, const float* __restrict__ b_out,
    const float* __restrict__ gamma, const float* __restrict__ beta,
    float* __restrict__ out) {
  const int node = blockIdx.x;
  const int tid = threadIdx.x;  // 0..127

  __shared__ float tok[9][D];
  __shared__ float kbuf[9][D];
  __shared__ float vbuf[9][D];
  __shared__ float q0[D];
  __shared__ float o0[D];
  __shared__ float attn_s[4][9];
  __shared__ int maskflag[9];
  __shared__ float wsum[2], wsq[2];

  // --- token 0: self ---
  tok[0][tid] = x[node * D + tid];

  // --- aggregate edge set 0 -> tokens 1..4 (max,min,sum,mean) ---
  {
    int s = off0[node], e = off0[node + 1];
    float sum = 0.0f, mx = -INFINITY, mn = INFINITY;
    for (int j = s; j < e; ++j) {
      int sr = list0[j];
      float v = x[sr * D + tid];
      sum += v;
      mx = fmaxf(mx, v);
      mn = fminf(mn, v);
    }
    int cnt = e - s;
    if (cnt == 0) { mx = 0.0f; mn = 0.0f; }
    tok[1][tid] = mx;
    tok[2][tid] = mn;
    tok[3][tid] = sum;
    tok[4][tid] = sum / (float)(cnt > 1 ? cnt : 1);
  }
  // --- aggregate edge set 1 -> tokens 5..8 ---
  {
    int s = off1[node], e = off1[node + 1];
    float sum = 0.0f, mx = -INFINITY, mn = INFINITY;
    for (int j = s; j < e; ++j) {
      int sr = list1[j];
      float v = x[sr * D + tid];
      sum += v;
      mx = fmaxf(mx, v);
      mn = fminf(mn, v);
    }
    int cnt = e - s;
    if (cnt == 0) { mx = 0.0f; mn = 0.0f; }
    tok[5][tid] = mx;
    tok[6][tid] = mn;
    tok[7][tid] = sum;
    tok[8][tid] = sum / (float)(cnt > 1 ? cnt : 1);
  }
  __syncthreads();

  // --- mask: token t (1..8) masked iff ALL 128 entries == 0 (faithful to ref) ---
  if (tid < 8) {
    int t = tid + 1;
    bool allz = true;
    for (int d = 0; d < D; ++d) allz = allz && (tok[t][d] == 0.0f);
    maskflag[t] = allz ? 1 : 0;
  }

  // --- qkv projection: thread j owns output column j ---
  {
    const int j = tid;
    const float4* wq = (const float4*)(w_in + (size_t)j * D);
    const float4* wk = (const float4*)(w_in + (size_t)(128 + j) * D);
    const float4* wv = (const float4*)(w_in + (size_t)(256 + j) * D);
    float accq = b_in[j];
    float bk = b_in[128 + j], bv = b_in[256 + j];
    float acck[9], accv[9];
#pragma unroll
    for (int t = 0; t < 9; ++t) { acck[t] = bk; accv[t] = bv; }

    for (int d4 = 0; d4 < D / 4; ++d4) {
      float4 a = wq[d4];
      float4 b = wk[d4];
      float4 c = wv[d4];
#pragma unroll
      for (int t = 0; t < 9; ++t) {
        float4 tv = ((const float4*)tok[t])[d4];
        if (t == 0) accq += a.x * tv.x + a.y * tv.y + a.z * tv.z + a.w * tv.w;
        acck[t] += b.x * tv.x + b.y * tv.y + b.z * tv.z + b.w * tv.w;
        accv[t] += c.x * tv.x + c.y * tv.y + c.z * tv.z + c.w * tv.w;
      }
    }
    q0[j] = accq;
#pragma unroll
    for (int t = 0; t < 9; ++t) {
      kbuf[t][j] = acck[t];
      vbuf[t][j] = accv[t];
    }
  }
  __syncthreads();

  // --- scores: 36 threads, (h,t) each ---
  if (tid < 36) {
    int h = tid / 9, t = tid % 9;
    float sc;
    if (t > 0 && maskflag[t]) {
      sc = -1e30f;
    } else {
      float s = 0.0f;
      for (int d = 0; d < 32; ++d) s += q0[h * 32 + d] * kbuf[t][h * 32 + d];
      sc = s * 0.17677669529663687f;  // 1/sqrt(32)
    }
    attn_s[h][t] = sc;
  }
  __syncthreads();

  // --- softmax over t per head ---
  if (tid < 4) {
    int h = tid;
    float m = -INFINITY;
#pragma unroll
    for (int t = 0; t < 9; ++t) m = fmaxf(m, attn_s[h][t]);
    float ev[9];
    float sum = 0.0f;
#pragma unroll
    for (int t = 0; t < 9; ++t) {
      ev[t] = __expf(attn_s[h][t] - m);
      sum += ev[t];
    }
    float inv = 1.0f / sum;
#pragma unroll
    for (int t = 0; t < 9; ++t) attn_s[h][t] = ev[t] * inv;
  }
  __syncthreads();

  // --- o0[d] = sum_t attn[h(d)][t] * v[t][d] ---
  {
    int h = tid >> 5;
    float o = 0.0f;
#pragma unroll
    for (int t = 0; t < 9; ++t) o += attn_s[h][t] * vbuf[t][tid];
    o0[tid] = o;
  }
  __syncthreads();

  // --- out = o0 @ w_out.T + b_out, then LayerNorm ---
  float acc;
  {
    const float4* wo = (const float4*)(w_out + (size_t)tid * D);
    acc = b_out[tid];
    for (int d4 = 0; d4 < D / 4; ++d4) {
      float4 w = wo[d4];
      float4 ov = ((const float4*)o0)[d4];
      acc += w.x * ov.x + w.y * ov.y + w.z * ov.z + w.w * ov.w;
    }
  }
  // block reduction for mean/var over 128 outputs
  float val = acc, sq = acc * acc;
#pragma unroll
  for (int m = 1; m < 64; m <<= 1) {
    val += __shfl_xor(val, m);
    sq += __shfl_xor(sq, m);
  }
  int wid = tid >> 6;
  if ((tid & 63) == 0) { wsum[wid] = val; wsq[wid] = sq; }
  __syncthreads();
  float tot = wsum[0] + wsum[1];
  float totsq = wsq[0] + wsq[1];
  float mu = tot * (1.0f / 128.0f);
  float var = totsq * (1.0f / 128.0f) - mu * mu;
  float r = rsqrtf(var + 1e-5f);
  out[node * D + tid] = (acc - mu) * r * gamma[tid] + beta[tid];
}

// ---------------- launch ----------------

extern "C" void kernel_launch(void* const* d_in, const int* in_sizes, int n_in,
                              void* d_out, int out_size, void* d_ws, size_t ws_size,
                              hipStream_t stream) {
  const float* x = (const float*)d_in[0];
  const int* ei0 = (const int*)d_in[1];
  const int* ei1 = (const int*)d_in[2];
  const float* w_in = (const float*)d_in[3];
  const float* b_in = (const float*)d_in[4];
  const float* w_out = (const float*)d_in[5];
  const float* b_out = (const float*)d_in[6];
  const float* gamma = (const float*)d_in[7];
  const float* beta = (const float*)d_in[8];
  float* out = (float*)d_out;

  int* ws = (int*)d_ws;
  int* cnt0 = ws;
  int* cnt1 = cnt0 + NNODES;
  int* off0 = cnt1 + NNODES;
  int* off1 = off0 + (NNODES + 1);
  int* cur0 = off1 + (NNODES + 1);
  int* cur1 = cur0 + NNODES;
  int* list0 = cur1 + NNODES;
  int* list1 = list0 + NEDGES;

  hipMemsetAsync(cnt0, 0, 2 * NNODES * sizeof(int), stream);

  int gE = (NEDGES + 255) / 256;
  count_kernel<<<gE, 256, 0, stream>>>(ei0, cnt0);
  count_kernel<<<gE, 256, 0, stream>>>(ei1, cnt1);
  scan_kernel<<<2, 1024, 0, stream>>>(cnt0, off0, cur0, cnt1, off1, cur1);
  scatter_kernel<<<gE, 256, 0, stream>>>(ei0, cur0, list0);
  scatter_kernel<<<gE, 256, 0, stream>>>(ei1, cur1, list1);
  fused_node_kernel<<<NNODES, 128, 0, stream>>>(x, off0, list0, off1, list1,
                                                w_in, b_in, w_out, b_out,
                                                gamma, beta, out);
}

// Round 2
// 607.186 us; speedup vs baseline: 4.6277x; 4.6277x over previous
//
#include <hip/hip_runtime.h>
#include <math.h>

#define NNODES 50000
#define NEDGES 800000
#define D 128
#define NPB 8          // nodes per fused block
#define ROWS (NPB * 9) // 72 token rows per fused block
#define MTILES 5       // 80 rows (8 zero-padded)

typedef _Float16 half_t;
typedef half_t half8 __attribute__((ext_vector_type(8)));
typedef float floatx4 __attribute__((ext_vector_type(4)));

// ---------------- CSR build ----------------

__global__ __launch_bounds__(256) void count_kernel(const int* __restrict__ ei,
                                                    int* __restrict__ cnt) {
  int e = blockIdx.x * 256 + threadIdx.x;
  if (e < NEDGES) atomicAdd(&cnt[ei[NEDGES + e]], 1);
}

__global__ __launch_bounds__(1024) void scan_kernel(
    const int* __restrict__ cnt0, int* __restrict__ off0, int* __restrict__ cur0,
    const int* __restrict__ cnt1, int* __restrict__ off1, int* __restrict__ cur1) {
  const int* cnt = (blockIdx.x == 0) ? cnt0 : cnt1;
  int* off = (blockIdx.x == 0) ? off0 : off1;
  int* cur = (blockIdx.x == 0) ? cur0 : cur1;
  __shared__ int sm[1024];
  int tid = threadIdx.x;
  int running = 0;
  for (int base = 0; base < NNODES; base += 1024) {
    int idx = base + tid;
    int v = (idx < NNODES) ? cnt[idx] : 0;
    sm[tid] = v;
    __syncthreads();
    for (int o = 1; o < 1024; o <<= 1) {
      int t = (tid >= o) ? sm[tid - o] : 0;
      __syncthreads();
      sm[tid] += t;
      __syncthreads();
    }
    int excl = running + sm[tid] - v;
    if (idx < NNODES) { off[idx] = excl; cur[idx] = excl; }
    running += sm[1023];
    __syncthreads();
  }
  if (tid == 0) off[NNODES] = running;
}

__global__ __launch_bounds__(256) void scatter_kernel(const int* __restrict__ ei,
                                                      int* __restrict__ cur,
                                                      int* __restrict__ list) {
  int e = blockIdx.x * 256 + threadIdx.x;
  if (e < NEDGES) {
    int s = ei[e];
    int d = ei[NEDGES + e];
    int pos = atomicAdd(&cur[d], 1);
    list[pos] = s;
  }
}

// ---------------- weight pre-swizzle (fp32 -> fp16 B-fragments) ----------------
// Chunk c = nt*4+ks holds 64 lanes x 8 half: lane l -> n = nt*16+(l&15),
// k = ks*32 + (l>>4)*8 + j. B-frag load becomes base + lane*16B (coalesced).

__global__ __launch_bounds__(256) void prep_w_kernel(const float* __restrict__ w_in,
                                                     const float* __restrict__ w_out,
                                                     half_t* __restrict__ w_swz,
                                                     half_t* __restrict__ wo_swz) {
  int slot = blockIdx.x * 256 + threadIdx.x;  // 8192 slots total
  const float* src;
  half_t* dst;
  int c, l;
  if (slot < 96 * 64) {
    c = slot >> 6; l = slot & 63;
    src = w_in; dst = w_swz + (size_t)slot * 8;
  } else {
    int s2 = slot - 96 * 64;
    c = s2 >> 6; l = s2 & 63;
    src = w_out; dst = wo_swz + (size_t)s2 * 8;
  }
  int nt = c >> 2, ks = c & 3;
  int n = nt * 16 + (l & 15);
  int kb = ks * 32 + (l >> 4) * 8;
#pragma unroll
  for (int j = 0; j < 8; ++j) dst[j] = (half_t)src[n * 128 + kb + j];
}

// ---------------- aggregation: node-parallel gather -> fp16 tokens ----------------

__global__ __launch_bounds__(128) void aggregate_kernel(
    const float* __restrict__ x,
    const int* __restrict__ off0, const int* __restrict__ list0,
    const int* __restrict__ off1, const int* __restrict__ list1,
    half_t* __restrict__ tok) {
  const int node = blockIdx.x;
  const int tid = threadIdx.x;  // = dim
  const size_t tb = (size_t)node * 9 * 128;

  tok[tb + tid] = (half_t)x[(size_t)node * 128 + tid];

#pragma unroll
  for (int set = 0; set < 2; ++set) {
    const int* off = set ? off1 : off0;
    const int* list = set ? list1 : list0;
    int s = off[node], e = off[node + 1];
    float sum = 0.0f, mx = -INFINITY, mn = INFINITY;
    int j = s;
    for (; j + 3 < e; j += 4) {  // 4 independent row loads in flight
      int i0 = list[j], i1 = list[j + 1], i2 = list[j + 2], i3 = list[j + 3];
      float v0 = x[(size_t)i0 * 128 + tid];
      float v1 = x[(size_t)i1 * 128 + tid];
      float v2 = x[(size_t)i2 * 128 + tid];
      float v3 = x[(size_t)i3 * 128 + tid];
      sum += (v0 + v1) + (v2 + v3);
      mx = fmaxf(mx, fmaxf(fmaxf(v0, v1), fmaxf(v2, v3)));
      mn = fminf(mn, fminf(fminf(v0, v1), fminf(v2, v3)));
    }
    for (; j < e; ++j) {
      int i0 = list[j];
      float v = x[(size_t)i0 * 128 + tid];
      sum += v; mx = fmaxf(mx, v); mn = fminf(mn, v);
    }
    int cnt = e - s;
    if (cnt == 0) { mx = 0.0f; mn = 0.0f; }
    size_t b = tb + (size_t)(1 + 4 * set) * 128;
    tok[b + tid] = (half_t)mx;
    tok[b + 128 + tid] = (half_t)mn;
    tok[b + 256 + tid] = (half_t)sum;
    tok[b + 384 + tid] = (half_t)(sum / (float)(cnt > 1 ? cnt : 1));
  }
}

// ---------------- fused MFMA projection + attention + w_out + LN ----------------
// 8 nodes/block, 256 threads (4 waves). LDS ~60.6 KB -> 2 blocks/CU.

__global__ __launch_bounds__(256, 2) void fused_attn_kernel(
    const half_t* __restrict__ tok16,
    const half_t* __restrict__ w_swz, const half_t* __restrict__ wo_swz,
    const float* __restrict__ b_in, const float* __restrict__ b_out,
    const int* __restrict__ off0, const int* __restrict__ off1,
    const float* __restrict__ gamma, const float* __restrict__ beta,
    float* __restrict__ out) {
  __shared__ half_t tokS[80 * 128];   // 20480 B; reused later: o16 [16x128] @0, oo fp32 [16x128] @byte 8192
  __shared__ half_t kvS[72 * 256];    // 36864 B: cols 0-127 = k, 128-255 = v
  __shared__ half_t qS[8 * 128];      // 2048 B: q of token 0 per node
  __shared__ float scS[8][4][9];
  __shared__ int cntS[8][2];

  const int tid = threadIdx.x;
  const int lane = tid & 63, wv = tid >> 6;
  const int quad = lane >> 4, l15 = lane & 15;

  // stage this block's 72 token rows (fp16, contiguous) + zero pad rows 72-79
  {
    const uint4* src = (const uint4*)(tok16 + (size_t)blockIdx.x * ROWS * 128);
    uint4* dst = (uint4*)tokS;
    for (int i = tid; i < 1280; i += 256)
      dst[i] = (i < 1152) ? src[i] : make_uint4(0, 0, 0, 0);
  }
  if (tid < 16) {
    int ln = tid >> 1, ss = tid & 1;
    int node = blockIdx.x * NPB + ln;
    const int* off = ss ? off1 : off0;
    cntS[ln][ss] = off[node + 1] - off[node];
  }
  __syncthreads();

  // GEMM1: C[80x384] = tok[80x128] @ w_in^T   (wave wv covers n-tiles wv, wv+4, ...)
  for (int mt = 0; mt < MTILES; ++mt) {
    half8 a[4];
#pragma unroll
    for (int ks = 0; ks < 4; ++ks)
      a[ks] = *(const half8*)(tokS + (mt * 16 + l15) * 128 + ks * 32 + quad * 8);
    for (int ntb = 0; ntb < 6; ++ntb) {
      int nt = wv + ntb * 4;
      floatx4 acc = {0.f, 0.f, 0.f, 0.f};
#pragma unroll
      for (int ks = 0; ks < 4; ++ks) {
        half8 b = *(const half8*)(w_swz + ((size_t)(nt * 4 + ks) * 64 + lane) * 8);
        acc = __builtin_amdgcn_mfma_f32_16x16x32_f16(a[ks], b, acc, 0, 0, 0);
      }
      int col = nt * 16 + l15;
      float bias = b_in[col];
#pragma unroll
      for (int r = 0; r < 4; ++r) {
        int row = mt * 16 + quad * 4 + r;
        if (row < ROWS) {
          float v = acc[r] + bias;
          if (col < 128) {
            if (row % 9 == 0) qS[(row / 9) * 128 + col] = (half_t)v;
          } else {
            kvS[row * 256 + (col - 128)] = (half_t)v;
          }
        }
      }
    }
  }
  __syncthreads();

  const int ln = tid >> 5, l5 = tid & 31;

  // scores (4 heads x 9 tokens per node; 32 lanes/node)
  {
    int h = l5 >> 3, t0 = l5 & 7;
    for (int t = t0; t < 9; t += 8) {
      float sc;
      bool masked = (t >= 1) && ((t <= 4) ? (cntS[ln][0] == 0) : (cntS[ln][1] == 0));
      if (masked) {
        sc = -1e30f;
      } else {
        const half_t* qp = qS + ln * 128 + h * 32;
        const half_t* kp = kvS + (ln * 9 + t) * 256 + h * 32;
        float acc = 0.f;
#pragma unroll
        for (int d2 = 0; d2 < 32; ++d2) acc += (float)qp[d2] * (float)kp[d2];
        sc = acc * 0.17677669529663687f;  // 1/sqrt(32)
      }
      scS[ln][h][t] = sc;
    }
  }
  __syncthreads();

  if (l5 < 4) {  // softmax per (node, head)
    int h = l5;
    float m = -INFINITY;
#pragma unroll
    for (int t = 0; t < 9; ++t) m = fmaxf(m, scS[ln][h][t]);
    float ev[9], sum = 0.f;
#pragma unroll
    for (int t = 0; t < 9; ++t) { ev[t] = __expf(scS[ln][h][t] - m); sum += ev[t]; }
    float inv = 1.f / sum;
#pragma unroll
    for (int t = 0; t < 9; ++t) scS[ln][h][t] = ev[t] * inv;
  }
  __syncthreads();

  // o0 = attn @ v  -> fp16 rows (node-major) reusing tokS bytes [0,4096)
  half_t* o16 = tokS;
  {
#pragma unroll
    for (int u = 0; u < 4; ++u) {
      int d2 = l5 * 4 + u;
      int h = d2 >> 5;
      float acc = 0.f;
#pragma unroll
      for (int t = 0; t < 9; ++t)
        acc += scS[ln][h][t] * (float)kvS[(ln * 9 + t) * 256 + 128 + d2];
      o16[ln * 128 + d2] = (half_t)acc;
    }
    if (tid < 128) ((uint4*)o16)[128 + tid] = make_uint4(0, 0, 0, 0);  // zero rows 8-15
  }
  __syncthreads();

  // GEMM2: oo[16x128] = o16[16x128] @ w_out^T  (+b_out), fp32 into tokS byte 8192
  float* oo = (float*)(tokS + 4096);
  {
    half8 a[4];
#pragma unroll
    for (int ks = 0; ks < 4; ++ks)
      a[ks] = *(const half8*)(o16 + l15 * 128 + ks * 32 + quad * 8);
    for (int ntb = 0; ntb < 2; ++ntb) {
      int nt = wv + ntb * 4;
      floatx4 acc = {0.f, 0.f, 0.f, 0.f};
#pragma unroll
      for (int ks = 0; ks < 4; ++ks) {
        half8 b = *(const half8*)(wo_swz + ((size_t)(nt * 4 + ks) * 64 + lane) * 8);
        acc = __builtin_amdgcn_mfma_f32_16x16x32_f16(a[ks], b, acc, 0, 0, 0);
      }
      int col = nt * 16 + l15;
#pragma unroll
      for (int r = 0; r < 4; ++r) {
        int row = quad * 4 + r;
        oo[row * 128 + col] = acc[r] + b_out[col];
      }
    }
  }
  __syncthreads();

  // LayerNorm per node (32 lanes x 4 cols)
  {
    float v[4];
    float sum = 0.f, sq = 0.f;
#pragma unroll
    for (int u = 0; u < 4; ++u) {
      int c = l5 * 4 + u;
      v[u] = oo[ln * 128 + c];
      sum += v[u];
      sq += v[u] * v[u];
    }
#pragma unroll
    for (int m = 1; m < 32; m <<= 1) {
      sum += __shfl_xor(sum, m);
      sq += __shfl_xor(sq, m);
    }
    float mu = sum * (1.f / 128.f);
    float var = sq * (1.f / 128.f) - mu * mu;
    float rs = rsqrtf(var + 1e-5f);
    int node = blockIdx.x * NPB + ln;
#pragma unroll
    for (int u = 0; u < 4; ++u) {
      int c = l5 * 4 + u;
      out[(size_t)node * 128 + c] = (v[u] - mu) * rs * gamma[c] + beta[c];
    }
  }
}

// ---------------- launch ----------------

extern "C" void kernel_launch(void* const* d_in, const int* in_sizes, int n_in,
                              void* d_out, int out_size, void* d_ws, size_t ws_size,
                              hipStream_t stream) {
  const float* x = (const float*)d_in[0];
  const int* ei0 = (const int*)d_in[1];
  const int* ei1 = (const int*)d_in[2];
  const float* w_in = (const float*)d_in[3];
  const float* b_in = (const float*)d_in[4];
  const float* w_out = (const float*)d_in[5];
  const float* b_out = (const float*)d_in[6];
  const float* gamma = (const float*)d_in[7];
  const float* beta = (const float*)d_in[8];
  float* out = (float*)d_out;

  char* wsB = (char*)d_ws;
  size_t off = 0;
  auto alloc_i = [&](size_t n) { int* p = (int*)(wsB + off); off += n * 4; return p; };
  int* cnt0 = alloc_i(NNODES);
  int* cnt1 = alloc_i(NNODES);
  int* off0 = alloc_i(NNODES + 1);
  int* off1 = alloc_i(NNODES + 1);
  int* cur0 = alloc_i(NNODES);
  int* cur1 = alloc_i(NNODES);
  int* list0 = alloc_i(NEDGES);
  int* list1 = alloc_i(NEDGES);
  off = (off + 15) & ~(size_t)15;
  half_t* w_swz = (half_t*)(wsB + off);  off += (size_t)96 * 64 * 8 * 2;
  half_t* wo_swz = (half_t*)(wsB + off); off += (size_t)32 * 64 * 8 * 2;
  half_t* tok16 = (half_t*)(wsB + off);  off += (size_t)NNODES * 9 * 128 * 2;

  hipMemsetAsync(cnt0, 0, 2 * NNODES * sizeof(int), stream);

  int gE = (NEDGES + 255) / 256;
  count_kernel<<<gE, 256, 0, stream>>>(ei0, cnt0);
  count_kernel<<<gE, 256, 0, stream>>>(ei1, cnt1);
  scan_kernel<<<2, 1024, 0, stream>>>(cnt0, off0, cur0, cnt1, off1, cur1);
  scatter_kernel<<<gE, 256, 0, stream>>>(ei0, cur0, list0);
  scatter_kernel<<<gE, 256, 0, stream>>>(ei1, cur1, list1);
  prep_w_kernel<<<32, 256, 0, stream>>>(w_in, w_out, w_swz, wo_swz);
  aggregate_kernel<<<NNODES, 128, 0, stream>>>(x, off0, list0, off1, list1, tok16);
  fused_attn_kernel<<<NNODES / NPB, 256, 0, stream>>>(tok16, w_swz, wo_swz, b_in, b_out,
                                                      off0, off1, gamma, beta, out);
}